// Round 3
// baseline (125.690 us; speedup 1.0000x reference)
//
#include <hip/hip_runtime.h>

// ViewLearner edge-MLP, three-stage structure:
//   K1 (node_uv): UV[n] = [ x_n @ W1[0:64] + b1 | x_n @ W1[64:128] ]  (fp16, 12.8 MB in ws)
//   K2 (edge_bin): bucket edges into 64 bins by (src/6250, dst/6250) -> (s,d,eid) recs.
//   K3 (edge_gather): bucket (sb,db) processed on XCD sb (blockIdx%8 round-robin),
//       db walked in order -> U-slice (1.6 MB) L2-resident all kernel, V-window
//       (1.6 MB) L2-resident per phase. Far-line traffic ~1.6M -> ~0.45M lines.
//
// Timing model: dur_us = ws-poison fill (47 us, immovable) + kernels. Round-2
// null result on MLP-doubling => edge phase is far-(L3/HBM)-throughput-bound,
// not latency-bound => locality is the remaining lever.

typedef __attribute__((ext_vector_type(8))) short short8;
typedef __attribute__((ext_vector_type(4))) float f32x4;
typedef __attribute__((ext_vector_type(8))) _Float16 half8;

__device__ __forceinline__ unsigned short f2bf_rne(float f) {
    union { float f; unsigned u; } v;
    v.f = f;
    return (unsigned short)((v.u + 0x7FFFu + ((v.u >> 16) & 1u)) >> 16);
}

#define W1T_K 72       // 64 + 8 shorts pad
#define CT_STRIDE 136  // 128 + 8 halfs pad

#define NBUCK 64
#define CAP 16384           // per-bucket record capacity (mu=12500, sigma~111)
#define CPB 256             // chunks (64-edge blocks) per bucket = CAP/64
#define SLICE_M 687195u     // __umulhi(n, M) == n/6250 exactly for n < 2.9M

// ws layout
#define UV_OFF   0                       // 50000*128 fp16 = 12.8 MB
#define CUR_OFF  (16u * 1024 * 1024)     // 64 int cursors
#define REC_OFF  (CUR_OFF + 4096)        // 64 * 16384 * 16 B = 16.8 MB

// ---- K1: per-node U|V table via 16x16x32 bf16 MFMA --------------------------
__global__ __launch_bounds__(256)
void node_uv(const float* __restrict__ X,
             const float* __restrict__ W1,
             const float* __restrict__ b1,
             _Float16* __restrict__ UV,
             int* __restrict__ cur,
             int nnodes, int ntiles) {
    // B matrix [k<64][j'<128]: j'<64 -> W1[k][j'] (U), j'>=64 -> W1[64+k][j'-64] (V)
    __shared__ __align__(16) unsigned short w1t[128 * W1T_K];
    __shared__ __align__(16) _Float16 cbuf[4][16 * CT_STRIDE];

    const int tid = threadIdx.x;
    if (blockIdx.x == 0 && tid < NBUCK) cur[tid] = 0;  // zero bin cursors for K2

#pragma unroll
    for (int i = 0; i < 32; ++i) {
        int idx = tid + i * 256;  // 8192 = 128*64 elements of W1, coalesced read
        int r = idx >> 6;         // W1 row (input dim) 0..127
        int col = idx & 63;       // W1 col (hidden)    0..63
        int k = r & 63;
        int jp = col + (r & 64);  // r>=64 -> V half (cols 64..127)
        w1t[jp * W1T_K + k] = f2bf_rne(W1[idx]);
    }
    __syncthreads();

    const int lane = tid & 63;
    const int wid = tid >> 6;
    const int c = lane & 15;
    const int quad = lane >> 4;

    const int t = blockIdx.x * 4 + wid;
    if (t >= ntiles) return;  // wave-uniform

    // B frags: bfrag[nt][kc] = B[k = kc*32+quad*8+j][col = nt*16+c]
    short8 bfrag[8][2];
#pragma unroll
    for (int nt = 0; nt < 8; ++nt)
#pragma unroll
        for (int kc = 0; kc < 2; ++kc)
            bfrag[nt][kc] =
                *(const short8*)&w1t[(nt * 16 + c) * W1T_K + kc * 32 + quad * 8];

    float b1v[8];
#pragma unroll
    for (int nt = 0; nt < 8; ++nt)
        b1v[nt] = (nt < 4) ? b1[nt * 16 + c] : 0.f;  // fold b1 into U half only

    // A row (node) loads: sequential rows, coalesced; convert fp32 -> bf16.
    int n = t * 16 + c;
    n = (n < nnodes) ? n : (nnodes - 1);
    const float* xr = X + (size_t)n * 64 + quad * 8;
    f32x4 x0a = *(const f32x4*)(xr);
    f32x4 x0b = *(const f32x4*)(xr + 4);
    f32x4 x1a = *(const f32x4*)(xr + 32);
    f32x4 x1b = *(const f32x4*)(xr + 36);
    short8 a0, a1;
#pragma unroll
    for (int i = 0; i < 4; ++i) {
        a0[i] = (short)f2bf_rne(x0a[i]);
        a0[4 + i] = (short)f2bf_rne(x0b[i]);
        a1[i] = (short)f2bf_rne(x1a[i]);
        a1[4 + i] = (short)f2bf_rne(x1b[i]);
    }

    f32x4 acc[8];
#pragma unroll
    for (int nt = 0; nt < 8; ++nt) acc[nt] = (f32x4){0.f, 0.f, 0.f, 0.f};
#pragma unroll
    for (int nt = 0; nt < 8; ++nt) {
        acc[nt] = __builtin_amdgcn_mfma_f32_16x16x32_bf16(a0, bfrag[nt][0], acc[nt], 0, 0, 0);
        acc[nt] = __builtin_amdgcn_mfma_f32_16x16x32_bf16(a1, bfrag[nt][1], acc[nt], 0, 0, 0);
    }

    // C layout: col j' = nt*16+c, row = quad*4+r. Repack via per-wave LDS region
    // to fp16, then coalesced 4 KB contiguous store.
    _Float16* cb = cbuf[wid];
#pragma unroll
    for (int nt = 0; nt < 8; ++nt)
#pragma unroll
        for (int r = 0; r < 4; ++r)
            cb[(quad * 4 + r) * CT_STRIDE + nt * 16 + c] =
                (_Float16)(acc[nt][r] + b1v[nt]);

    __builtin_amdgcn_s_waitcnt(0);  // drain ds_writes before cross-lane ds_read

    // lane l copies 32 halfs: global flat g = l*32 + i -> row g/128, col g%128
    const _Float16* rp = &cb[(lane >> 2) * CT_STRIDE + (lane & 3) * 32];
    const f32x4* s4 = (const f32x4*)rp;
    f32x4* dst = (f32x4*)(UV + (size_t)t * 2048 + lane * 32);
    dst[0] = s4[0];
    dst[1] = s4[1];
    dst[2] = s4[2];
    dst[3] = s4[3];
}

// ---- K2: bin edges by (src-slice, dst-slice) into 64 buckets ----------------
__global__ __launch_bounds__(256)
void edge_bin(const int* __restrict__ eidx,
              const _Float16* __restrict__ UV,
              const float* __restrict__ W2,
              const float* __restrict__ b2,
              int* __restrict__ cur,
              int4* __restrict__ recs,
              float* __restrict__ out, int E) {
    __shared__ int lhist[NBUCK], lbase[NBUCK], loff[NBUCK];
    const int tid = threadIdx.x;
    if (tid < NBUCK) { lhist[tid] = 0; loff[tid] = 0; }
    __syncthreads();

    const int base = blockIdx.x * 1024;
    int s[4], d[4], bk[4];
#pragma unroll
    for (int i = 0; i < 4; ++i) {
        int e = base + i * 256 + tid;
        if (e < E) {
            s[i] = __builtin_nontemporal_load(eidx + e);
            d[i] = __builtin_nontemporal_load(eidx + E + e);
            bk[i] = (int)(__umulhi((unsigned)s[i], SLICE_M) * 8u +
                          __umulhi((unsigned)d[i], SLICE_M));
            atomicAdd(&lhist[bk[i]], 1);
        } else {
            bk[i] = -1;
        }
    }
    __syncthreads();
    if (tid < NBUCK && lhist[tid] > 0)
        lbase[tid] = atomicAdd(&cur[tid], lhist[tid]);
    __syncthreads();
#pragma unroll
    for (int i = 0; i < 4; ++i) {
        if (bk[i] < 0) continue;
        int e = base + i * 256 + tid;
        int slot = lbase[bk[i]] + atomicAdd(&loff[bk[i]], 1);
        if (slot < CAP) {
            recs[bk[i] * CAP + slot] = make_int4(s[i], d[i], e, 0);
        } else {
            // overflow fallback (35-sigma event; correctness insurance only)
            float acc = 0.f;
            const _Float16* up = UV + (size_t)s[i] * 128;
            const _Float16* vp = UV + (size_t)d[i] * 128 + 64;
            for (int k = 0; k < 64; ++k)
                acc += fmaxf((float)up[k] + (float)vp[k], 0.f) * W2[k];
            out[e] = acc + b2[0];
        }
    }
}

// ---- K3: bucketed gather + relu + dot(W2); XCD sb owns src-slice sb ---------
__global__ __launch_bounds__(256)
void edge_gather(const int4* __restrict__ recs,
                 const int* __restrict__ cur,
                 const _Float16* __restrict__ UV,
                 const float* __restrict__ W2,
                 const float* __restrict__ b2,
                 float* __restrict__ out) {
    const int tid = threadIdx.x;
    const int sb = blockIdx.x & 7;       // -> XCD sb (round-robin heuristic)
    const int r = blockIdx.x >> 3;
    const int db = r >> 8;               // r / CPB ; dst window walks in order
    const int chunk = r & (CPB - 1);
    const int b = sb * 8 + db;
    const int cnt = min(cur[b], CAP);
    const int w0 = chunk * 64;
    if (w0 >= cnt) return;               // wave-uniform early exit

    const int slot = tid >> 3;           // 32 edge-slots, 2 edges each
    const int j = tid & 7;
    const int4* rb = recs + (size_t)b * CAP;
    const f32x4 w2a = *(const f32x4*)(W2 + j * 8);
    const f32x4 w2b = *(const f32x4*)(W2 + j * 8 + 4);
    const float b2v = b2[0];

    int ea = w0 + slot;
    int eb = w0 + 32 + slot;
    const bool va = ea < cnt;
    const bool vb = eb < cnt;
    ea = va ? ea : 0;
    eb = vb ? eb : 0;
    const int4 ra = rb[ea];              // 8 lanes broadcast one 16-B rec
    const int4 rc = rb[eb];

    half8 u0 = *(const half8*)(UV + (size_t)ra.x * 128 + j * 8);
    half8 v0 = *(const half8*)(UV + (size_t)ra.y * 128 + 64 + j * 8);
    half8 u1 = *(const half8*)(UV + (size_t)rc.x * 128 + j * 8);
    half8 v1 = *(const half8*)(UV + (size_t)rc.y * 128 + 64 + j * 8);

    float a0 = 0.f, a1 = 0.f;
#pragma unroll
    for (int i = 0; i < 4; ++i) {
        a0 = fmaf(fmaxf((float)u0[i] + (float)v0[i], 0.f), w2a[i], a0);
        a0 = fmaf(fmaxf((float)u0[4 + i] + (float)v0[4 + i], 0.f), w2b[i], a0);
        a1 = fmaf(fmaxf((float)u1[i] + (float)v1[i], 0.f), w2a[i], a1);
        a1 = fmaf(fmaxf((float)u1[4 + i] + (float)v1[4 + i], 0.f), w2b[i], a1);
    }
    a0 += __shfl_xor(a0, 1, 8);
    a0 += __shfl_xor(a0, 2, 8);
    a0 += __shfl_xor(a0, 4, 8);
    a1 += __shfl_xor(a1, 1, 8);
    a1 += __shfl_xor(a1, 2, 8);
    a1 += __shfl_xor(a1, 4, 8);
    if (j == 0) {
        if (va) out[ra.z] = a0 + b2v;
        if (vb) out[rc.z] = a1 + b2v;
    }
}

extern "C" void kernel_launch(void* const* d_in, const int* in_sizes, int n_in,
                              void* d_out, int out_size, void* d_ws, size_t ws_size,
                              hipStream_t stream) {
    const float* X = (const float*)d_in[0];
    const int* eidx = (const int*)d_in[1];
    const float* W1 = (const float*)d_in[2];
    const float* b1 = (const float*)d_in[3];
    const float* W2 = (const float*)d_in[4];
    const float* b2 = (const float*)d_in[5];
    float* out = (float*)d_out;

    const int nnodes = in_sizes[0] / 64;
    const int E = in_sizes[1] / 2;

    char* ws = (char*)d_ws;
    _Float16* UV = (_Float16*)(ws + UV_OFF);   // [nnodes][128] fp16, 12.8 MB
    int* cur = (int*)(ws + CUR_OFF);           // 64 bucket cursors
    int4* recs = (int4*)(ws + REC_OFF);        // 64 x 16384 x 16 B

    const int ntiles = (nnodes + 15) / 16;
    node_uv<<<(ntiles + 3) / 4, 256, 0, stream>>>(X, W1, b1, UV, cur, nnodes, ntiles);

    const int nbin = (E + 1023) / 1024;
    edge_bin<<<nbin, 256, 0, stream>>>(eidx, UV, W2, b2, cur, recs, out, E);

    edge_gather<<<NBUCK * CPB, 256, 0, stream>>>(recs, cur, UV, W2, b2, out);
}

// Round 4
// 124.794 us; speedup vs baseline: 1.0072x; 1.0072x over previous
//
#include <hip/hip_runtime.h>

// ViewLearner edge-MLP, three-stage with cheap 64-way locality binning:
//   K1 (node_uv): UV[n] = [ x_n @ W1[0:64] + b1 | x_n @ W1[64:128] ] (fp16, 12.8 MB)
//   K2 (edge_bin): bucket edges by (src/6250, dst/6250) into 64 bins.
//       8-B packed records, LDS-staged, coalesced 64-B flush runs,
//       ONE LDS atomic per edge + 64 global atomics per block.
//   K3 (edge_gather): bucket (sb,db) on XCD sb (blockIdx&7), db windows walked
//       in launch order -> U-slice (0.8 MB) + V-window (~0.8 MB) L2-resident.
//       Chunk records staged through LDS; nontemporal on all streams.
//
// r3 post-mortem fixes: no scattered 16-B record writes (was ~1 line per 16 B),
// 1 LDS atomic/edge (was 2 + global reservation), 8-B records (was 16 B).

typedef __attribute__((ext_vector_type(8))) short short8;
typedef __attribute__((ext_vector_type(4))) float f32x4;
typedef __attribute__((ext_vector_type(8))) _Float16 half8;
typedef unsigned long long u64;

__device__ __forceinline__ unsigned short f2bf_rne(float f) {
    union { float f; unsigned u; } v;
    v.f = f;
    return (unsigned short)((v.u + 0x7FFFu + ((v.u >> 16) & 1u)) >> 16);
}

#define W1T_K 72       // 64 + 8 shorts pad
#define CT_STRIDE 136  // 128 + 8 halfs pad

#define NBUCK 64
#define GCAP 16384          // per-bucket global record cap (mu=12500, sigma~111)
#define CHUNK 128           // edges per K3 block
#define CPB (GCAP / CHUNK)  // 128 chunks per bucket
#define K2_BLK 1024         // edges per K2 block
#define LCAP 64             // per-(block,bucket) LDS cap (mu=16, ~12 sigma)
#define SLICE_M 687195u     // __umulhi(n, M) == n/6250 for n < 50000

// ws layout
#define UV_OFF  0                        // 50000*128 fp16 = 12.8 MB
#define CUR_OFF (16u * 1024 * 1024)      // 64 int cursors
#define REC_OFF (CUR_OFF + 4096)         // 64 * 16384 * 8 B = 8 MB

__device__ __forceinline__ float edge_eval(const _Float16* __restrict__ UV,
                                           const float* __restrict__ W2,
                                           float b2v, unsigned s, unsigned d) {
    float acc = 0.f;
    const _Float16* up = UV + (size_t)s * 128;
    const _Float16* vp = UV + (size_t)d * 128 + 64;
    for (int k = 0; k < 64; ++k)
        acc += fmaxf((float)up[k] + (float)vp[k], 0.f) * W2[k];
    return acc + b2v;
}

// ---- K1: per-node U|V table via 16x16x32 bf16 MFMA --------------------------
__global__ __launch_bounds__(256)
void node_uv(const float* __restrict__ X,
             const float* __restrict__ W1,
             const float* __restrict__ b1,
             _Float16* __restrict__ UV,
             int* __restrict__ cur,
             int nnodes, int ntiles) {
    __shared__ __align__(16) unsigned short w1t[128 * W1T_K];
    __shared__ __align__(16) _Float16 cbuf[4][16 * CT_STRIDE];

    const int tid = threadIdx.x;
    if (blockIdx.x == 0 && tid < NBUCK) cur[tid] = 0;  // zero bin cursors for K2

#pragma unroll
    for (int i = 0; i < 32; ++i) {
        int idx = tid + i * 256;  // 8192 = 128*64 elements of W1, coalesced read
        int r = idx >> 6;
        int col = idx & 63;
        int k = r & 63;
        int jp = col + (r & 64);  // r>=64 -> V half (cols 64..127)
        w1t[jp * W1T_K + k] = f2bf_rne(W1[idx]);
    }
    __syncthreads();

    const int lane = tid & 63;
    const int wid = tid >> 6;
    const int c = lane & 15;
    const int quad = lane >> 4;

    const int t = blockIdx.x * 4 + wid;
    if (t >= ntiles) return;  // wave-uniform

    short8 bfrag[8][2];
#pragma unroll
    for (int nt = 0; nt < 8; ++nt)
#pragma unroll
        for (int kc = 0; kc < 2; ++kc)
            bfrag[nt][kc] =
                *(const short8*)&w1t[(nt * 16 + c) * W1T_K + kc * 32 + quad * 8];

    float b1v[8];
#pragma unroll
    for (int nt = 0; nt < 8; ++nt)
        b1v[nt] = (nt < 4) ? b1[nt * 16 + c] : 0.f;  // fold b1 into U half only

    int n = t * 16 + c;
    n = (n < nnodes) ? n : (nnodes - 1);
    const float* xr = X + (size_t)n * 64 + quad * 8;
    f32x4 x0a = *(const f32x4*)(xr);
    f32x4 x0b = *(const f32x4*)(xr + 4);
    f32x4 x1a = *(const f32x4*)(xr + 32);
    f32x4 x1b = *(const f32x4*)(xr + 36);
    short8 a0, a1;
#pragma unroll
    for (int i = 0; i < 4; ++i) {
        a0[i] = (short)f2bf_rne(x0a[i]);
        a0[4 + i] = (short)f2bf_rne(x0b[i]);
        a1[i] = (short)f2bf_rne(x1a[i]);
        a1[4 + i] = (short)f2bf_rne(x1b[i]);
    }

    f32x4 acc[8];
#pragma unroll
    for (int nt = 0; nt < 8; ++nt) acc[nt] = (f32x4){0.f, 0.f, 0.f, 0.f};
#pragma unroll
    for (int nt = 0; nt < 8; ++nt) {
        acc[nt] = __builtin_amdgcn_mfma_f32_16x16x32_bf16(a0, bfrag[nt][0], acc[nt], 0, 0, 0);
        acc[nt] = __builtin_amdgcn_mfma_f32_16x16x32_bf16(a1, bfrag[nt][1], acc[nt], 0, 0, 0);
    }

    _Float16* cb = cbuf[wid];
#pragma unroll
    for (int nt = 0; nt < 8; ++nt)
#pragma unroll
        for (int r = 0; r < 4; ++r)
            cb[(quad * 4 + r) * CT_STRIDE + nt * 16 + c] =
                (_Float16)(acc[nt][r] + b1v[nt]);

    __builtin_amdgcn_s_waitcnt(0);  // drain ds_writes before cross-lane ds_read

    const _Float16* rp = &cb[(lane >> 2) * CT_STRIDE + (lane & 3) * 32];
    const f32x4* s4 = (const f32x4*)rp;
    f32x4* dst = (f32x4*)(UV + (size_t)t * 2048 + lane * 32);
    dst[0] = s4[0];
    dst[1] = s4[1];
    dst[2] = s4[2];
    dst[3] = s4[3];
}

// ---- K2: bin edges into 64 buckets; LDS-staged, coalesced flush -------------
__global__ __launch_bounds__(256)
void edge_bin(const int* __restrict__ eidx,
              const _Float16* __restrict__ UV,
              const float* __restrict__ W2,
              const float* __restrict__ b2,
              int* __restrict__ cur,
              u64* __restrict__ recs,
              float* __restrict__ out, int E) {
    __shared__ u64 lrec[NBUCK][LCAP + 1];  // +1: spread buckets across banks
    __shared__ int lcnt[NBUCK];
    __shared__ int gbase[NBUCK];
    const int tid = threadIdx.x;
    if (tid < NBUCK) lcnt[tid] = 0;
    __syncthreads();

    const int base = blockIdx.x * K2_BLK;
#pragma unroll
    for (int i = 0; i < 4; ++i) {
        int e = base + i * 256 + tid;
        if (e >= E) continue;
        unsigned s = (unsigned)__builtin_nontemporal_load(eidx + e);
        unsigned d = (unsigned)__builtin_nontemporal_load(eidx + E + e);
        int bk = (int)(__umulhi(s, SLICE_M) * 8u + __umulhi(d, SLICE_M));
        u64 rec = ((u64)(unsigned)e << 32) | (u64)((s << 16) | d);
        int slot = atomicAdd(&lcnt[bk], 1);
        if (slot < LCAP) {
            lrec[bk][slot] = rec;
        } else {  // LDS overflow (>=12 sigma): direct global tail append
            int gs = atomicAdd(&cur[bk], 1);
            if (gs < GCAP) recs[(size_t)bk * GCAP + gs] = rec;
            else out[e] = edge_eval(UV, W2, b2[0], s, d);
        }
    }
    __syncthreads();

    if (tid < NBUCK) {
        int c = min(lcnt[tid], LCAP);
        gbase[tid] = atomicAdd(&cur[tid], c);
    }
    __syncthreads();

    // coalesced flush: 2 rounds x (32 buckets x 8 lanes), 64-B write runs
#pragma unroll
    for (int r = 0; r < 2; ++r) {
        int b = (tid >> 3) + r * 32;
        int k = tid & 7;
        int c = min(lcnt[b], LCAP);
        int gb = gbase[b];
        for (int idx = k; idx < c; idx += 8) {
            u64 rec = lrec[b][idx];
            int gs = gb + idx;
            if (gs < GCAP) {
                __builtin_nontemporal_store(rec, recs + (size_t)b * GCAP + gs);
            } else {
                unsigned sd = (unsigned)rec;
                out[(unsigned)(rec >> 32)] =
                    edge_eval(UV, W2, b2[0], sd >> 16, sd & 0xFFFFu);
            }
        }
    }
}

// ---- K3: bucketed gather + relu + dot(W2); XCD sb owns src-slice sb ---------
__global__ __launch_bounds__(256)
void edge_gather(const u64* __restrict__ recs,
                 const int* __restrict__ cur,
                 const _Float16* __restrict__ UV,
                 const float* __restrict__ W2,
                 const float* __restrict__ b2,
                 float* __restrict__ out) {
    __shared__ u64 crec[CHUNK];
    const int tid = threadIdx.x;
    const int sb = blockIdx.x & 7;   // -> XCD sb (round-robin heuristic)
    const int r = blockIdx.x >> 3;
    const int db = r / CPB;          // dst window: walks in launch order
    const int chunk = r - db * CPB;
    const int b = sb * 8 + db;
    const int cnt = min(cur[b], GCAP);
    const int w0 = chunk * CHUNK;
    if (w0 >= cnt) return;  // block-uniform exit (before any barrier)

    if (tid < CHUNK) {
        int i = w0 + tid;
        crec[tid] = (i < cnt) ? __builtin_nontemporal_load(recs + (size_t)b * GCAP + i)
                              : 0ULL;
    }
    __syncthreads();

    const int slot = tid >> 3;  // 32 groups of 8 lanes; 4 edges per group
    const int j = tid & 7;
    const f32x4 w2a = *(const f32x4*)(W2 + j * 8);
    const f32x4 w2b = *(const f32x4*)(W2 + j * 8 + 4);
    const float b2v = b2[0];

    half8 u[4], v[4];
    unsigned eid[4];
    bool val[4];
#pragma unroll
    for (int i = 0; i < 4; ++i) {
        int idx = slot + i * 32;
        val[i] = (w0 + idx) < cnt;
        u64 rec = crec[idx];
        unsigned sd = (unsigned)rec;
        unsigned s = val[i] ? (sd >> 16) : 0u;
        unsigned d = val[i] ? (sd & 0xFFFFu) : 0u;
        eid[i] = (unsigned)(rec >> 32);
        u[i] = *(const half8*)(UV + (size_t)s * 128 + j * 8);
        v[i] = *(const half8*)(UV + (size_t)d * 128 + 64 + j * 8);
    }

#pragma unroll
    for (int i = 0; i < 4; ++i) {
        float a = 0.f;
#pragma unroll
        for (int k = 0; k < 4; ++k) {
            a = fmaf(fmaxf((float)u[i][k] + (float)v[i][k], 0.f), w2a[k], a);
            a = fmaf(fmaxf((float)u[i][4 + k] + (float)v[i][4 + k], 0.f), w2b[k], a);
        }
        a += __shfl_xor(a, 1, 8);
        a += __shfl_xor(a, 2, 8);
        a += __shfl_xor(a, 4, 8);
        if (j == 0 && val[i]) out[eid[i]] = a + b2v;
    }
}

extern "C" void kernel_launch(void* const* d_in, const int* in_sizes, int n_in,
                              void* d_out, int out_size, void* d_ws, size_t ws_size,
                              hipStream_t stream) {
    const float* X = (const float*)d_in[0];
    const int* eidx = (const int*)d_in[1];
    const float* W1 = (const float*)d_in[2];
    const float* b1 = (const float*)d_in[3];
    const float* W2 = (const float*)d_in[4];
    const float* b2 = (const float*)d_in[5];
    float* out = (float*)d_out;

    const int nnodes = in_sizes[0] / 64;
    const int E = in_sizes[1] / 2;

    char* ws = (char*)d_ws;
    _Float16* UV = (_Float16*)(ws + UV_OFF);
    int* cur = (int*)(ws + CUR_OFF);
    u64* recs = (u64*)(ws + REC_OFF);

    const int ntiles = (nnodes + 15) / 16;
    node_uv<<<(ntiles + 3) / 4, 256, 0, stream>>>(X, W1, b1, UV, cur, nnodes, ntiles);

    edge_bin<<<(E + K2_BLK - 1) / K2_BLK, 256, 0, stream>>>(eidx, UV, W2, b2, cur,
                                                            recs, out, E);

    edge_gather<<<NBUCK * CPB, 256, 0, stream>>>(recs, cur, UV, W2, b2, out);
}

// Round 5
// 105.223 us; speedup vs baseline: 1.1945x; 1.1860x over previous
//
#include <hip/hip_runtime.h>

// ViewLearner edge-MLP, two-kernel structure (r2 baseline = best, 103 us),
// with persistent-grid + 2-stage software-pipelined edge phase:
//   K1 (node_uv): UV[n] = [ x_n @ W1[0:64] + b1 | x_n @ W1[64:128] ] (fp16, 12.8 MB ws)
//   K2 (edge_out): persistent 2048-block grid, 8 lanes/edge, grid-stride;
//       while computing edge i, gathers for i+1 are in flight and indices for
//       i+2 are loading. ~12 edges/thread amortize wave setup/drain.
//
// History: locality binning (r3/r4: 125.7/124.8 us, two different machineries,
// identical cost) => gather is NOT far-BW-bound; MLP-widening (r2) null =>
// not wave-level-MLP-bound. This round tests thread-churn/pipeline depth.
// Pre-commit: if this is null (~103), declare roofline next round.

typedef __attribute__((ext_vector_type(8))) short short8;
typedef __attribute__((ext_vector_type(4))) float f32x4;
typedef __attribute__((ext_vector_type(8))) _Float16 half8;

__device__ __forceinline__ unsigned short f2bf_rne(float f) {
    union { float f; unsigned u; } v;
    v.f = f;
    return (unsigned short)((v.u + 0x7FFFu + ((v.u >> 16) & 1u)) >> 16);
}

#define W1T_K 72       // 64 + 8 shorts pad
#define CT_STRIDE 136  // 128 + 8 halfs pad

// ---- K1: per-node U|V table via 16x16x32 bf16 MFMA --------------------------
__global__ __launch_bounds__(256)
void node_uv(const float* __restrict__ X,
             const float* __restrict__ W1,
             const float* __restrict__ b1,
             _Float16* __restrict__ UV,
             int nnodes, int ntiles) {
    // B matrix [k<64][j'<128]: j'<64 -> W1[k][j'] (U), j'>=64 -> W1[64+k][j'-64] (V)
    __shared__ __align__(16) unsigned short w1t[128 * W1T_K];
    __shared__ __align__(16) _Float16 cbuf[4][16 * CT_STRIDE];

    const int tid = threadIdx.x;
#pragma unroll
    for (int i = 0; i < 32; ++i) {
        int idx = tid + i * 256;  // 8192 = 128*64 elements of W1, coalesced read
        int r = idx >> 6;
        int col = idx & 63;
        int k = r & 63;
        int jp = col + (r & 64);  // r>=64 -> V half (cols 64..127)
        w1t[jp * W1T_K + k] = f2bf_rne(W1[idx]);
    }
    __syncthreads();

    const int lane = tid & 63;
    const int wid = tid >> 6;
    const int c = lane & 15;
    const int quad = lane >> 4;

    const int t = blockIdx.x * 4 + wid;
    if (t >= ntiles) return;  // wave-uniform

    short8 bfrag[8][2];
#pragma unroll
    for (int nt = 0; nt < 8; ++nt)
#pragma unroll
        for (int kc = 0; kc < 2; ++kc)
            bfrag[nt][kc] =
                *(const short8*)&w1t[(nt * 16 + c) * W1T_K + kc * 32 + quad * 8];

    float b1v[8];
#pragma unroll
    for (int nt = 0; nt < 8; ++nt)
        b1v[nt] = (nt < 4) ? b1[nt * 16 + c] : 0.f;  // fold b1 into U half only

    int n = t * 16 + c;
    n = (n < nnodes) ? n : (nnodes - 1);
    const float* xr = X + (size_t)n * 64 + quad * 8;
    f32x4 x0a = *(const f32x4*)(xr);
    f32x4 x0b = *(const f32x4*)(xr + 4);
    f32x4 x1a = *(const f32x4*)(xr + 32);
    f32x4 x1b = *(const f32x4*)(xr + 36);
    short8 a0, a1;
#pragma unroll
    for (int i = 0; i < 4; ++i) {
        a0[i] = (short)f2bf_rne(x0a[i]);
        a0[4 + i] = (short)f2bf_rne(x0b[i]);
        a1[i] = (short)f2bf_rne(x1a[i]);
        a1[4 + i] = (short)f2bf_rne(x1b[i]);
    }

    f32x4 acc[8];
#pragma unroll
    for (int nt = 0; nt < 8; ++nt) acc[nt] = (f32x4){0.f, 0.f, 0.f, 0.f};
#pragma unroll
    for (int nt = 0; nt < 8; ++nt) {
        acc[nt] = __builtin_amdgcn_mfma_f32_16x16x32_bf16(a0, bfrag[nt][0], acc[nt], 0, 0, 0);
        acc[nt] = __builtin_amdgcn_mfma_f32_16x16x32_bf16(a1, bfrag[nt][1], acc[nt], 0, 0, 0);
    }

    // C layout: col j' = nt*16+c, row = quad*4+r. Repack via per-wave LDS region
    // to fp16, then coalesced 4 KB contiguous store.
    _Float16* cb = cbuf[wid];
#pragma unroll
    for (int nt = 0; nt < 8; ++nt)
#pragma unroll
        for (int r = 0; r < 4; ++r)
            cb[(quad * 4 + r) * CT_STRIDE + nt * 16 + c] =
                (_Float16)(acc[nt][r] + b1v[nt]);

    __builtin_amdgcn_s_waitcnt(0);  // drain ds_writes before cross-lane ds_read

    const _Float16* rp = &cb[(lane >> 2) * CT_STRIDE + (lane & 3) * 32];
    const f32x4* s4 = (const f32x4*)rp;
    f32x4* dst = (f32x4*)(UV + (size_t)t * 2048 + lane * 32);
    dst[0] = s4[0];
    dst[1] = s4[1];
    dst[2] = s4[2];
    dst[3] = s4[3];
}

// ---- K2: persistent grid-stride, 8 lanes/edge, 2-stage pipeline -------------
__global__ __launch_bounds__(256)
void edge_out(const int* __restrict__ eidx,
              const _Float16* __restrict__ UV,
              const float* __restrict__ W2,
              const float* __restrict__ b2,
              float* __restrict__ out, int E) {
    const int tid = blockIdx.x * 256 + threadIdx.x;
    const int j = tid & 7;               // hidden chunk [j*8, j*8+8)
    const int step = (gridDim.x * 256) >> 3;  // edge-slots in the grid

    int e0 = tid >> 3;
    if (e0 >= E) return;

    const f32x4 w2a = *(const f32x4*)(W2 + j * 8);
    const f32x4 w2b = *(const f32x4*)(W2 + j * 8 + 4);
    const float b2v = b2[0];

    // stage 0: indices + gathers for e0 in flight
    int s0 = __builtin_nontemporal_load(eidx + e0);
    int d0 = __builtin_nontemporal_load(eidx + E + e0);
    half8 u0 = *(const half8*)(UV + (size_t)s0 * 128 + j * 8);
    half8 v0 = *(const half8*)(UV + (size_t)d0 * 128 + 64 + j * 8);

    // stage 1: indices for e1 in flight
    int e1 = e0 + step;
    bool m1 = e1 < E;
    int e1c = m1 ? e1 : e0;
    int s1 = __builtin_nontemporal_load(eidx + e1c);
    int d1 = __builtin_nontemporal_load(eidx + E + e1c);

    while (true) {
        // issue gathers for e1 (overlaps compute of e0)
        half8 u1 = *(const half8*)(UV + (size_t)s1 * 128 + j * 8);
        half8 v1 = *(const half8*)(UV + (size_t)d1 * 128 + 64 + j * 8);

        // prefetch indices for e2
        int e2 = e1 + step;
        bool m2 = m1 && (e2 < E);
        int e2c = m2 ? e2 : e0;
        int s2 = __builtin_nontemporal_load(eidx + e2c);
        int d2 = __builtin_nontemporal_load(eidx + E + e2c);

        // compute + store e0
        float a = 0.f;
#pragma unroll
        for (int i = 0; i < 4; ++i) {
            a = fmaf(fmaxf((float)u0[i] + (float)v0[i], 0.f), w2a[i], a);
            a = fmaf(fmaxf((float)u0[4 + i] + (float)v0[4 + i], 0.f), w2b[i], a);
        }
        a += __shfl_xor(a, 1, 8);
        a += __shfl_xor(a, 2, 8);
        a += __shfl_xor(a, 4, 8);
        if (j == 0) __builtin_nontemporal_store(a + b2v, out + e0);

        if (!m1) break;
        e0 = e1; u0 = u1; v0 = v1;
        e1 = e2; m1 = m2; s1 = s2; d1 = d2;
    }
}

extern "C" void kernel_launch(void* const* d_in, const int* in_sizes, int n_in,
                              void* d_out, int out_size, void* d_ws, size_t ws_size,
                              hipStream_t stream) {
    const float* X = (const float*)d_in[0];
    const int* eidx = (const int*)d_in[1];
    const float* W1 = (const float*)d_in[2];
    const float* b1 = (const float*)d_in[3];
    const float* W2 = (const float*)d_in[4];
    const float* b2 = (const float*)d_in[5];
    float* out = (float*)d_out;

    const int nnodes = in_sizes[0] / 64;
    const int E = in_sizes[1] / 2;

    _Float16* UV = (_Float16*)d_ws;  // [nnodes][128] fp16, ~12.8 MB

    const int ntiles = (nnodes + 15) / 16;
    node_uv<<<(ntiles + 3) / 4, 256, 0, stream>>>(X, W1, b1, UV, nnodes, ntiles);

    // persistent grid: 2048 blocks = 8 blocks/CU (max 256-thread occupancy);
    // 65536 edge-slots -> ~12 edges/thread amortize setup/drain.
    int nthreads = E * 8;
    int grid = (nthreads + 255) / 256;
    if (grid > 2048) grid = 2048;
    edge_out<<<grid, 256, 0, stream>>>(eidx, UV, W2, b2, out, E);
}

// Round 6
// 102.948 us; speedup vs baseline: 1.2209x; 1.0221x over previous
//
#include <hip/hip_runtime.h>

// ViewLearner edge-MLP — FINAL: two-kernel structure, best measured (103.0 us, r2).
//   K1 (node_uv): UV[n] = [ x_n @ W1[0:64] + b1 | x_n @ W1[64:128] ]  (fp16, 12.8 MB in ws)
//       -- one small MFMA GEMM over nodes (sequential rows, no gather). ~5 us.
//   K2 (edge_out): out[e] = relu(UV[src][0:64] + UV[dst][64:128]) . W2 + b2
//       -- 2 edges per thread (e, e+E/2): 4 independent line-coalesced gathers
//          in flight per lane; nt loads for eidx, nt store for out. ~44 us.
//
// Measured lever matrix (r0-r5): MLP widening null; 64-way XCD-affine locality
// null twice (machinery >= 25 us vs <= 20 us savings); persistence/pipelining
// null; fusion -2.8x. edge_out sits at ~4.7 TB/s effective line-gather rate
// (~75-80% of the machine's demonstrated far-path BW) with compulsory bytes:
// 1.6M x 128-B lines. dur_us additionally carries a ~47 us harness ws-poison
// fill inside the timed window. This is the roofline for this structure.

typedef __attribute__((ext_vector_type(8))) short short8;
typedef __attribute__((ext_vector_type(4))) float f32x4;
typedef __attribute__((ext_vector_type(8))) _Float16 half8;

__device__ __forceinline__ unsigned short f2bf_rne(float f) {
    union { float f; unsigned u; } v;
    v.f = f;
    return (unsigned short)((v.u + 0x7FFFu + ((v.u >> 16) & 1u)) >> 16);
}

#define W1T_K 72       // 64 + 8 shorts pad
#define CT_STRIDE 136  // 128 + 8 halfs pad

// ---- K1: per-node U|V table via 16x16x32 bf16 MFMA --------------------------
__global__ __launch_bounds__(256)
void node_uv(const float* __restrict__ X,
             const float* __restrict__ W1,
             const float* __restrict__ b1,
             _Float16* __restrict__ UV,
             int nnodes, int ntiles) {
    // B matrix [k<64][j'<128]: j'<64 -> W1[k][j'] (U), j'>=64 -> W1[64+k][j'-64] (V)
    __shared__ __align__(16) unsigned short w1t[128 * W1T_K];
    __shared__ __align__(16) _Float16 cbuf[4][16 * CT_STRIDE];

    const int tid = threadIdx.x;
#pragma unroll
    for (int i = 0; i < 32; ++i) {
        int idx = tid + i * 256;  // 8192 = 128*64 elements of W1, coalesced read
        int r = idx >> 6;         // W1 row (input dim) 0..127
        int col = idx & 63;       // W1 col (hidden)    0..63
        int k = r & 63;
        int jp = col + (r & 64);  // r>=64 -> V half (cols 64..127)
        w1t[jp * W1T_K + k] = f2bf_rne(W1[idx]);
    }
    __syncthreads();

    const int lane = tid & 63;
    const int wid = tid >> 6;
    const int c = lane & 15;
    const int quad = lane >> 4;

    const int t = blockIdx.x * 4 + wid;
    if (t >= ntiles) return;  // wave-uniform

    // B frags: bfrag[nt][kc] = B[k = kc*32+quad*8+j][col = nt*16+c]
    short8 bfrag[8][2];
#pragma unroll
    for (int nt = 0; nt < 8; ++nt)
#pragma unroll
        for (int kc = 0; kc < 2; ++kc)
            bfrag[nt][kc] =
                *(const short8*)&w1t[(nt * 16 + c) * W1T_K + kc * 32 + quad * 8];

    float b1v[8];
#pragma unroll
    for (int nt = 0; nt < 8; ++nt)
        b1v[nt] = (nt < 4) ? b1[nt * 16 + c] : 0.f;  // fold b1 into U half only

    // A row (node) loads: sequential rows, coalesced; convert fp32 -> bf16.
    int n = t * 16 + c;
    n = (n < nnodes) ? n : (nnodes - 1);
    const float* xr = X + (size_t)n * 64 + quad * 8;
    f32x4 x0a = *(const f32x4*)(xr);
    f32x4 x0b = *(const f32x4*)(xr + 4);
    f32x4 x1a = *(const f32x4*)(xr + 32);
    f32x4 x1b = *(const f32x4*)(xr + 36);
    short8 a0, a1;
#pragma unroll
    for (int i = 0; i < 4; ++i) {
        a0[i] = (short)f2bf_rne(x0a[i]);
        a0[4 + i] = (short)f2bf_rne(x0b[i]);
        a1[i] = (short)f2bf_rne(x1a[i]);
        a1[4 + i] = (short)f2bf_rne(x1b[i]);
    }

    f32x4 acc[8];
#pragma unroll
    for (int nt = 0; nt < 8; ++nt) acc[nt] = (f32x4){0.f, 0.f, 0.f, 0.f};
#pragma unroll
    for (int nt = 0; nt < 8; ++nt) {
        acc[nt] = __builtin_amdgcn_mfma_f32_16x16x32_bf16(a0, bfrag[nt][0], acc[nt], 0, 0, 0);
        acc[nt] = __builtin_amdgcn_mfma_f32_16x16x32_bf16(a1, bfrag[nt][1], acc[nt], 0, 0, 0);
    }

    // C layout: col j' = nt*16+c, row = quad*4+r. Repack via per-wave LDS region
    // to fp16, then coalesced 4 KB contiguous store (UV tile rows are contiguous).
    _Float16* cb = cbuf[wid];
#pragma unroll
    for (int nt = 0; nt < 8; ++nt)
#pragma unroll
        for (int r = 0; r < 4; ++r)
            cb[(quad * 4 + r) * CT_STRIDE + nt * 16 + c] =
                (_Float16)(acc[nt][r] + b1v[nt]);

    __builtin_amdgcn_s_waitcnt(0);  // drain ds_writes before cross-lane ds_read

    // lane l copies 32 halfs: global flat g = l*32 + i -> row g/128, col g%128
    const _Float16* rp = &cb[(lane >> 2) * CT_STRIDE + (lane & 3) * 32];
    const f32x4* s4 = (const f32x4*)rp;
    f32x4* dst = (f32x4*)(UV + (size_t)t * 2048 + lane * 32);
    dst[0] = s4[0];
    dst[1] = s4[1];
    dst[2] = s4[2];
    dst[3] = s4[3];
}

// ---- K2: per-edge gather + relu + dot(W2), 2 edges per thread ---------------
__global__ __launch_bounds__(256)
void edge_out(const int* __restrict__ eidx,
              const _Float16* __restrict__ UV,
              const float* __restrict__ W2,
              const float* __restrict__ b2,
              float* __restrict__ out, int E, int Ehalf) {
    int tid = blockIdx.x * 256 + threadIdx.x;
    int e0 = tid >> 3;      // 8 lanes per edge
    int j = tid & 7;        // hidden chunk [j*8, j*8+8)
    if (e0 >= Ehalf) return;
    int e1 = e0 + Ehalf;
    bool has1 = (e1 < E);

    // eidx: single-use stream -> nontemporal (keep L2 for the UV table)
    int s0 = __builtin_nontemporal_load(eidx + e0);
    int d0 = __builtin_nontemporal_load(eidx + E + e0);
    int e1c = has1 ? e1 : e0;
    int s1 = __builtin_nontemporal_load(eidx + e1c);
    int d1 = __builtin_nontemporal_load(eidx + E + e1c);

    // 4 independent 16B gathers; each edge's 8 lanes cover one 128B line.
    half8 u0 = *(const half8*)(UV + (size_t)s0 * 128 + j * 8);
    half8 v0 = *(const half8*)(UV + (size_t)d0 * 128 + 64 + j * 8);
    half8 u1 = *(const half8*)(UV + (size_t)s1 * 128 + j * 8);
    half8 v1 = *(const half8*)(UV + (size_t)d1 * 128 + 64 + j * 8);

    f32x4 w2a = *(const f32x4*)(W2 + j * 8);
    f32x4 w2b = *(const f32x4*)(W2 + j * 8 + 4);
    const float b2v = b2[0];

    float a0 = 0.f, a1 = 0.f;
#pragma unroll
    for (int i = 0; i < 4; ++i) {
        a0 = fmaf(fmaxf((float)u0[i] + (float)v0[i], 0.f), w2a[i], a0);
        a0 = fmaf(fmaxf((float)u0[4 + i] + (float)v0[4 + i], 0.f), w2b[i], a0);
        a1 = fmaf(fmaxf((float)u1[i] + (float)v1[i], 0.f), w2a[i], a1);
        a1 = fmaf(fmaxf((float)u1[4 + i] + (float)v1[4 + i], 0.f), w2b[i], a1);
    }
    a0 += __shfl_xor(a0, 1, 8);
    a0 += __shfl_xor(a0, 2, 8);
    a0 += __shfl_xor(a0, 4, 8);
    a1 += __shfl_xor(a1, 1, 8);
    a1 += __shfl_xor(a1, 2, 8);
    a1 += __shfl_xor(a1, 4, 8);
    if (j == 0) {
        __builtin_nontemporal_store(a0 + b2v, out + e0);
        if (has1) __builtin_nontemporal_store(a1 + b2v, out + e1);
    }
}

extern "C" void kernel_launch(void* const* d_in, const int* in_sizes, int n_in,
                              void* d_out, int out_size, void* d_ws, size_t ws_size,
                              hipStream_t stream) {
    const float* X = (const float*)d_in[0];
    const int* eidx = (const int*)d_in[1];
    const float* W1 = (const float*)d_in[2];
    const float* b1 = (const float*)d_in[3];
    const float* W2 = (const float*)d_in[4];
    const float* b2 = (const float*)d_in[5];
    float* out = (float*)d_out;

    const int nnodes = in_sizes[0] / 64;
    const int E = in_sizes[1] / 2;

    _Float16* UV = (_Float16*)d_ws;  // [nnodes_padded][128] fp16, ~12.8 MB

    const int ntiles = (nnodes + 15) / 16;
    node_uv<<<(ntiles + 3) / 4, 256, 0, stream>>>(X, W1, b1, UV, nnodes, ntiles);

    const int Ehalf = (E + 1) / 2;
    const int nthreads = Ehalf * 8;
    edge_out<<<(nthreads + 255) / 256, 256, 0, stream>>>(eidx, UV, W2, b2, out, E, Ehalf);
}